// Round 3
// baseline (1434.280 us; speedup 1.0000x reference)
//
#include <hip/hip_runtime.h>
#include <hip/hip_bf16.h>
#include <cstdint>
#include <cstddef>

typedef __bf16 bf16;
typedef __attribute__((ext_vector_type(8))) __bf16 bf16x8;
typedef __attribute__((ext_vector_type(4))) float f32x4;

// ---------------------------------------------------------------------------
// weight transpose+cast: src (L,K,N) fp32 -> dst (L,N,K) bf16. grid(N/32,K/32,L)
// ---------------------------------------------------------------------------
__global__ __launch_bounds__(256) void wtrans(const float* __restrict__ src,
    bf16* __restrict__ dst, int K, int N) {
  __shared__ float tile[32][33];
  int l = blockIdx.z;
  src += (size_t)l * K * N; dst += (size_t)l * K * N;
  int n0 = blockIdx.x * 32, k0 = blockIdx.y * 32;
  int tx = threadIdx.x & 31, ty = threadIdx.x >> 5;
#pragma unroll
  for (int i = 0; i < 4; i++) {
    int k = ty + i * 8;
    tile[k][tx] = src[(size_t)(k0 + k) * N + n0 + tx];
  }
  __syncthreads();
#pragma unroll
  for (int i = 0; i < 4; i++) {
    int n = ty + i * 8;
    dst[(size_t)(n0 + n) * K + k0 + tx] = (bf16)tile[tx][n];
  }
}

// ---------------------------------------------------------------------------
// conv1 (3x3, 3->16, VALID) + ReLU + maxpool 2x2 via MFMA (implicit im2col).
// x (16,512,512,3) fp32 -> out bf16 (16,255,255,16).
// Block = 16x16 pooled outputs; grid (16,16,16), 4 waves.
// ---------------------------------------------------------------------------
__global__ __launch_bounds__(256) void conv1_mfma(const float* __restrict__ x,
    const float* __restrict__ w, const float* __restrict__ bias,
    bf16* __restrict__ out) {
  __shared__ alignas(16) bf16 xs[34 * 35 * 8];   // 19040 B
  int t = threadIdx.x;
  int bx = blockIdx.x, by = blockIdx.y, b = blockIdx.z;
  int r0 = 32 * by, c0 = 32 * bx;
  for (int i = t; i < 34 * 35; i += 256) {
    int rr = i / 35, cc = i % 35;
    int gr = min(r0 + rr, 511), gc = min(c0 + cc, 511);
    const float* ip = x + ((size_t)(b * 512 + gr) * 512 + gc) * 3;
    bf16x8 pv = {(bf16)ip[0], (bf16)ip[1], (bf16)ip[2],
                 (bf16)0.f, (bf16)0.f, (bf16)0.f, (bf16)0.f, (bf16)0.f};
    *(bf16x8*)&xs[i * 8] = pv;
  }
  int lane = t & 63, wave = t >> 6;
  int lr = lane & 15, lq = lane >> 4;
  bf16x8 bfrag[3];
#pragma unroll
  for (int ky = 0; ky < 3; ky++) {
    bf16x8 v;
#pragma unroll
    for (int j = 0; j < 8; j++)
      v[j] = (lq < 3 && j < 3) ? (bf16)w[((ky * 3 + lq) * 3 + j) * 16 + lr] : (bf16)0.f;
    bfrag[ky] = v;
  }
  float bco = bias[lr];
  __syncthreads();
#pragma unroll
  for (int yy = 0; yy < 4; yy++) {
    int Y = wave * 4 + yy;            // pooled row within tile
    int yp = by * 16 + Y;
    int cy = 2 * Y;                   // conv row (halo-local)
#pragma unroll
    for (int hx = 0; hx < 2; hx++) {
      f32x4 a0 = {0.f, 0.f, 0.f, 0.f}, a1 = {0.f, 0.f, 0.f, 0.f};
      int pbase = hx * 16 + lr + lq;  // A row = conv-x (lr), octet = kx (lq)
#pragma unroll
      for (int ky = 0; ky < 3; ky++) {
        bf16x8 f0 = *(const bf16x8*)&xs[((cy + ky) * 35 + pbase) * 8];
        a0 = __builtin_amdgcn_mfma_f32_16x16x32_bf16(f0, bfrag[ky], a0, 0, 0, 0);
      }
#pragma unroll
      for (int ky = 0; ky < 3; ky++) {
        bf16x8 f1 = *(const bf16x8*)&xs[((cy + 1 + ky) * 35 + pbase) * 8];
        a1 = __builtin_amdgcn_mfma_f32_16x16x32_bf16(f1, bfrag[ky], a1, 0, 0, 0);
      }
      float m0 = fmaxf(fmaxf(a0[0], a0[1]), fmaxf(a1[0], a1[1]));
      float m1 = fmaxf(fmaxf(a0[2], a0[3]), fmaxf(a1[2], a1[3]));
      m0 = fmaxf(m0 + bco, 0.f);
      m1 = fmaxf(m1 + bco, 0.f);
      int xp0 = bx * 16 + hx * 8 + 2 * lq, xp1 = xp0 + 1;
      if (yp < 255) {
        bf16* op = out + ((size_t)(b * 255 + yp) * 255) * 16 + lr;
        if (xp0 < 255) op[xp0 * 16] = (bf16)m0;
        if (xp1 < 255) op[xp1 * 16] = (bf16)m1;
      }
    }
  }
}

// ---------------------------------------------------------------------------
// conv2 + ReLU + maxpool + pad(1) + patch-extract via MFMA (implicit im2col).
// in bf16 (16,255,255,16); block = one 16x16 patch; grid (8,8,16), 4 waves.
// ---------------------------------------------------------------------------
__global__ __launch_bounds__(256) void conv2_mfma(const bf16* __restrict__ in,
    const float* __restrict__ w, const float* __restrict__ bias,
    bf16* __restrict__ patches) {
  __shared__ alignas(16) bf16 xlo[1156 * 8];   // 34x34 positions, ch 0-7
  __shared__ alignas(16) bf16 xhi[1156 * 8];   // ch 8-15
  __shared__ float ws[2304];
  int t = threadIdx.x;
  int tx = blockIdx.x, ty = blockIdx.y, b = blockIdx.z;
  for (int i = t; i < 2304; i += 256) ws[i] = w[i];
  int r0 = 32 * ty - 2, c0 = 32 * tx - 2;
  for (int i = t; i < 1156; i += 256) {
    int rr = i / 34, cc = i % 34;
    int gr = min(max(r0 + rr, 0), 254), gc = min(max(c0 + cc, 0), 254);
    const bf16* ip = in + ((size_t)(b * 255 + gr) * 255 + gc) * 16;
    *(uint4*)&xlo[i * 8] = *(const uint4*)ip;
    *(uint4*)&xhi[i * 8] = *(const uint4*)(ip + 8);
  }
  __syncthreads();
  int lane = t & 63, wave = t >> 6;
  int lr = lane & 15, lq = lane >> 4;
  int tapsel = lq >> 1;
  int ci0 = (lq & 1) * 8;
  bf16x8 bfrag[5];
  int koff[5];   // (ky*34 + kx) address offset for this lane's tap, per chunk
#pragma unroll
  for (int c2 = 0; c2 < 5; c2++) {
    int tap = 2 * c2 + tapsel;
    bf16x8 v;
#pragma unroll
    for (int j = 0; j < 8; j++)
      v[j] = (tap < 9) ? (bf16)ws[tap * 256 + (ci0 + j) * 16 + lr] : (bf16)0.f;
    bfrag[c2] = v;
    int tc = min(tap, 8);                    // pad tap reads tap-8 addr (x 0 weight)
    koff[c2] = (tc / 3) * 34 + (tc % 3);
  }
  const bf16* plane = (lq & 1) ? xhi : xlo;
  float bco = bias[lr];
  bf16* pout = patches + ((size_t)(b * 64 + ty * 8 + tx) * 4096);
#pragma unroll
  for (int yy = 0; yy < 4; yy++) {
    int Y = wave * 4 + yy;
    int yp = ty * 16 + Y;
    bool padrow = (yp == 0 || yp == 127);
#pragma unroll
    for (int hx = 0; hx < 2; hx++) {
      f32x4 a0 = {0.f, 0.f, 0.f, 0.f}, a1 = {0.f, 0.f, 0.f, 0.f};
      int base0 = (2 * Y) * 34 + hx * 16 + lr;   // conv row 2Y, x = hx*16+lr
      int base1 = base0 + 34;                    // conv row 2Y+1
#pragma unroll
      for (int c2 = 0; c2 < 5; c2++) {
        bf16x8 f0 = *(const bf16x8*)&plane[(base0 + koff[c2]) * 8];
        a0 = __builtin_amdgcn_mfma_f32_16x16x32_bf16(f0, bfrag[c2], a0, 0, 0, 0);
      }
#pragma unroll
      for (int c2 = 0; c2 < 5; c2++) {
        bf16x8 f1 = *(const bf16x8*)&plane[(base1 + koff[c2]) * 8];
        a1 = __builtin_amdgcn_mfma_f32_16x16x32_bf16(f1, bfrag[c2], a1, 0, 0, 0);
      }
      float m0 = fmaxf(fmaxf(a0[0], a0[1]), fmaxf(a1[0], a1[1]));
      float m1 = fmaxf(fmaxf(a0[2], a0[3]), fmaxf(a1[2], a1[3]));
      m0 = fmaxf(m0 + bco, 0.f);
      m1 = fmaxf(m1 + bco, 0.f);
      int px0 = hx * 8 + 2 * lq, px1 = px0 + 1;
      int xp0 = tx * 16 + px0, xp1 = xp0 + 1;
      if (padrow || xp0 == 0) m0 = 0.f;      // xp0==127 impossible (even)
      if (padrow || xp1 == 127) m1 = 0.f;    // xp1==0 impossible (odd)
      pout[Y * 256 + px0 * 16 + lr] = (bf16)m0;
      pout[Y * 256 + px1 * 16 + lr] = (bf16)m1;
    }
  }
}

// ---------------------------------------------------------------------------
// bf16 MFMA GEMM: C = A(M,K) @ Bt(N,K)^T. Barrier-free, LDS-free.
// Block = 256 threads = 4 independent 64x64 wave-tiles in a 128x128 block-tile
// (2x2: waves sharing A rows / B cols dedupe via L1/L2). Each wave loads MFMA
// fragments DIRECTLY from global (lane reads 16B at (row+lr)*K + lq*8) and
// accumulates acc[4][4]; per K=32 step: 8 global_load_dwordx4 : 16 MFMA,
// zero LDS, zero __syncthreads -> no barrier drain, compiler pipelines loads.
// MODE 0: fp32 partial, no bias. MODE 1: bias+relu -> bf16.
// ---------------------------------------------------------------------------
template<int MODE>
__device__ __forceinline__ void gemm_core(const bf16* __restrict__ A,
    const bf16* __restrict__ Bt, const float* __restrict__ bias,
    float* __restrict__ Cf, bf16* __restrict__ Cb,
    int bm, int bn, int N, int K, int k0, int kc) {
  int lane = threadIdx.x & 63, wave = threadIdx.x >> 6;
  int wm = bm + (wave >> 1) * 64, wn = bn + (wave & 1) * 64;
  int lq = lane >> 4, lr = lane & 15;
  f32x4 acc[4][4];
#pragma unroll
  for (int i = 0; i < 4; i++)
#pragma unroll
  for (int j = 0; j < 4; j++) acc[i][j] = (f32x4){0.f, 0.f, 0.f, 0.f};
  const bf16* Ap0 = A + (size_t)(wm + lr) * K + k0 + lq * 8;
  const bf16* Bp0 = Bt + (size_t)(wn + lr) * K + k0 + lq * 8;
  size_t r16 = (size_t)16 * K;
  const bf16* Ap1 = Ap0 + r16;       const bf16* Bp1 = Bp0 + r16;
  const bf16* Ap2 = Ap1 + r16;       const bf16* Bp2 = Bp1 + r16;
  const bf16* Ap3 = Ap2 + r16;       const bf16* Bp3 = Bp2 + r16;
#pragma unroll 2
  for (int kk = 0; kk < kc; kk += 32) {
    bf16x8 af0 = *(const bf16x8*)Ap0, af1 = *(const bf16x8*)Ap1;
    bf16x8 af2 = *(const bf16x8*)Ap2, af3 = *(const bf16x8*)Ap3;
    bf16x8 bf0 = *(const bf16x8*)Bp0, bf1 = *(const bf16x8*)Bp1;
    bf16x8 bf2 = *(const bf16x8*)Bp2, bf3 = *(const bf16x8*)Bp3;
    Ap0 += 32; Ap1 += 32; Ap2 += 32; Ap3 += 32;
    Bp0 += 32; Bp1 += 32; Bp2 += 32; Bp3 += 32;
    acc[0][0] = __builtin_amdgcn_mfma_f32_16x16x32_bf16(af0, bf0, acc[0][0], 0, 0, 0);
    acc[0][1] = __builtin_amdgcn_mfma_f32_16x16x32_bf16(af0, bf1, acc[0][1], 0, 0, 0);
    acc[0][2] = __builtin_amdgcn_mfma_f32_16x16x32_bf16(af0, bf2, acc[0][2], 0, 0, 0);
    acc[0][3] = __builtin_amdgcn_mfma_f32_16x16x32_bf16(af0, bf3, acc[0][3], 0, 0, 0);
    acc[1][0] = __builtin_amdgcn_mfma_f32_16x16x32_bf16(af1, bf0, acc[1][0], 0, 0, 0);
    acc[1][1] = __builtin_amdgcn_mfma_f32_16x16x32_bf16(af1, bf1, acc[1][1], 0, 0, 0);
    acc[1][2] = __builtin_amdgcn_mfma_f32_16x16x32_bf16(af1, bf2, acc[1][2], 0, 0, 0);
    acc[1][3] = __builtin_amdgcn_mfma_f32_16x16x32_bf16(af1, bf3, acc[1][3], 0, 0, 0);
    acc[2][0] = __builtin_amdgcn_mfma_f32_16x16x32_bf16(af2, bf0, acc[2][0], 0, 0, 0);
    acc[2][1] = __builtin_amdgcn_mfma_f32_16x16x32_bf16(af2, bf1, acc[2][1], 0, 0, 0);
    acc[2][2] = __builtin_amdgcn_mfma_f32_16x16x32_bf16(af2, bf2, acc[2][2], 0, 0, 0);
    acc[2][3] = __builtin_amdgcn_mfma_f32_16x16x32_bf16(af2, bf3, acc[2][3], 0, 0, 0);
    acc[3][0] = __builtin_amdgcn_mfma_f32_16x16x32_bf16(af3, bf0, acc[3][0], 0, 0, 0);
    acc[3][1] = __builtin_amdgcn_mfma_f32_16x16x32_bf16(af3, bf1, acc[3][1], 0, 0, 0);
    acc[3][2] = __builtin_amdgcn_mfma_f32_16x16x32_bf16(af3, bf2, acc[3][2], 0, 0, 0);
    acc[3][3] = __builtin_amdgcn_mfma_f32_16x16x32_bf16(af3, bf3, acc[3][3], 0, 0, 0);
  }
#pragma unroll
  for (int mi = 0; mi < 4; mi++)
#pragma unroll
  for (int ni = 0; ni < 4; ni++) {
    int col = wn + ni * 16 + lr;
#pragma unroll
    for (int rr = 0; rr < 4; rr++) {
      int row = wm + mi * 16 + lq * 4 + rr;   // m89-verified C/D layout
      float v = acc[mi][ni][rr];
      if (MODE == 1) {
        v = fmaxf(v + bias[col], 0.f);
        Cb[(size_t)row * N + col] = (bf16)v;
      } else {
        Cf[(size_t)row * N + col] = v;
      }
    }
  }
}

template<int MODE>
__global__ __launch_bounds__(256) void gemm_std(const bf16* __restrict__ A,
    const bf16* __restrict__ Bt, const float* __restrict__ bias,
    float* __restrict__ Cf, bf16* __restrict__ Cb, int N, int K, int KC) {
  int s = blockIdx.z;
  float* Cfp = Cf ? Cf + (size_t)s * 1024 * N : nullptr;
  gemm_core<MODE>(A, Bt, bias, Cfp, Cb, blockIdx.y * 128, blockIdx.x * 128, N, K, s * KC, KC);
}

__global__ __launch_bounds__(256) void gemm_qkv(const bf16* __restrict__ A,
    const bf16* __restrict__ Btq, const bf16* __restrict__ Btk, const bf16* __restrict__ Btv,
    float* __restrict__ qp, float* __restrict__ kp, float* __restrict__ vp) {
  int z = blockIdx.z;               // 0..5 : sel*2 + split
  int sel = z >> 1, s = z & 1;
  const bf16* Bt = (sel == 0) ? Btq : (sel == 1) ? Btk : Btv;
  float* C = ((sel == 0) ? qp : (sel == 1) ? kp : vp) + (size_t)s * 786432;
  gemm_core<0>(A, Bt, nullptr, C, nullptr, blockIdx.y * 128, blockIdx.x * 128, 768, 768, s * 384, 384);
}

// ---------------------------------------------------------------------------
// attention: one block per (b,h). q,k,v are 2-way split-K fp32 partials
// (2,1024,768); bias added here. Output (B,H,S,D)-flat bf16 (reference quirk).
// ---------------------------------------------------------------------------
__global__ __launch_bounds__(256) void attn_kernel(const float* __restrict__ Qp,
    const float* __restrict__ Kp, const float* __restrict__ Vp,
    const float* __restrict__ bq, const float* __restrict__ bk, const float* __restrict__ bv,
    bf16* __restrict__ Aout) {
  __shared__ alignas(16) float qs[64 * 68];   // later reused as V^T [d][s]
  __shared__ alignas(16) float ks[64 * 68];
  __shared__ alignas(16) float ss[64 * 68];
  int t = threadIdx.x;
  int bh = blockIdx.x; int b = bh / 12, h = bh % 12;
  size_t base = (size_t)b * 49152 + h * 64;
  const float* qb0 = Qp + base; const float* qb1 = qb0 + 786432;
  const float* kb0 = Kp + base; const float* kb1 = kb0 + 786432;
  const float* vb0 = Vp + base; const float* vb1 = vb0 + 786432;
  {
    int s = t >> 2, qd = (t & 3) * 16;
#pragma unroll
    for (int j = 0; j < 16; j += 4) {
      float4 q0 = *(const float4*)(qb0 + (size_t)s * 768 + qd + j);
      float4 q1 = *(const float4*)(qb1 + (size_t)s * 768 + qd + j);
      float4 qb4 = *(const float4*)(bq + h * 64 + qd + j);
      float4 k0 = *(const float4*)(kb0 + (size_t)s * 768 + qd + j);
      float4 k1 = *(const float4*)(kb1 + (size_t)s * 768 + qd + j);
      float4 kb4 = *(const float4*)(bk + h * 64 + qd + j);
      qs[s * 68 + qd + j + 0] = q0.x + q1.x + qb4.x;
      qs[s * 68 + qd + j + 1] = q0.y + q1.y + qb4.y;
      qs[s * 68 + qd + j + 2] = q0.z + q1.z + qb4.z;
      qs[s * 68 + qd + j + 3] = q0.w + q1.w + qb4.w;
      ks[s * 68 + qd + j + 0] = k0.x + k1.x + kb4.x;
      ks[s * 68 + qd + j + 1] = k0.y + k1.y + kb4.y;
      ks[s * 68 + qd + j + 2] = k0.z + k1.z + kb4.z;
      ks[s * 68 + qd + j + 3] = k0.w + k1.w + kb4.w;
    }
  }
  __syncthreads();
  int r = t >> 4, c = t & 15;
  {
    float sc[4][4];
#pragma unroll
    for (int i = 0; i < 4; i++)
#pragma unroll
    for (int j = 0; j < 4; j++) sc[i][j] = 0.f;
    for (int k = 0; k < 64; k += 4) {
      float4 qv[4], kv[4];
#pragma unroll
      for (int i = 0; i < 4; i++) qv[i] = *(const float4*)&qs[(r + 16 * i) * 68 + k];
#pragma unroll
      for (int j = 0; j < 4; j++) kv[j] = *(const float4*)&ks[(c + 16 * j) * 68 + k];
#pragma unroll
      for (int i = 0; i < 4; i++)
#pragma unroll
      for (int j = 0; j < 4; j++)
        sc[i][j] += qv[i].x * kv[j].x + qv[i].y * kv[j].y + qv[i].z * kv[j].z + qv[i].w * kv[j].w;
    }
#pragma unroll
    for (int i = 0; i < 4; i++)
#pragma unroll
    for (int j = 0; j < 4; j++)
      ss[(r + 16 * i) * 68 + c + 16 * j] = sc[i][j] * 0.125f;
  }
  __syncthreads();
  {  // V^T into qs with partial-sum + bias
    int d = t & 63, s0 = (t >> 6) * 16;
    float bvd = bv[h * 64 + d];
    alignas(16) float vv[16];
#pragma unroll
    for (int i = 0; i < 16; i++)
      vv[i] = vb0[(size_t)(s0 + i) * 768 + d] + vb1[(size_t)(s0 + i) * 768 + d] + bvd;
#pragma unroll
    for (int i = 0; i < 16; i += 4) *(float4*)&qs[d * 68 + s0 + i] = *(float4*)&vv[i];
  }
  {  // softmax
    int lane = t & 63, wave = t >> 6;
    for (int rr = 0; rr < 16; rr++) {
      int row = wave * 16 + rr;
      float v = ss[row * 68 + lane];
      float m = v;
#pragma unroll
      for (int off = 32; off > 0; off >>= 1) m = fmaxf(m, __shfl_xor(m, off));
      float e = __expf(v - m);
      float ssum = e;
#pragma unroll
      for (int off = 32; off > 0; off >>= 1) ssum += __shfl_xor(ssum, off);
      ss[row * 68 + lane] = e / ssum;
    }
  }
  __syncthreads();
  {
    float oc[4][4];
#pragma unroll
    for (int i = 0; i < 4; i++)
#pragma unroll
    for (int j = 0; j < 4; j++) oc[i][j] = 0.f;
    for (int k = 0; k < 64; k += 4) {
      float4 pv[4], vv[4];
#pragma unroll
      for (int i = 0; i < 4; i++) pv[i] = *(const float4*)&ss[(r + 16 * i) * 68 + k];
#pragma unroll
      for (int j = 0; j < 4; j++) vv[j] = *(const float4*)&qs[(c + 16 * j) * 68 + k];
#pragma unroll
      for (int i = 0; i < 4; i++)
#pragma unroll
      for (int j = 0; j < 4; j++)
        oc[i][j] += pv[i].x * vv[j].x + pv[i].y * vv[j].y + pv[i].z * vv[j].z + pv[i].w * vv[j].w;
    }
    bf16* ob = Aout + (size_t)b * 49152 + h * 4096;
#pragma unroll
    for (int i = 0; i < 4; i++)
#pragma unroll
    for (int j = 0; j < 4; j++)
      ob[(r + 16 * i) * 64 + c + 16 * j] = (bf16)oc[i][j];
  }
}

// ---------------------------------------------------------------------------
// residual + S-way split-K partial sum + col bias + LayerNorm; fp32 + bf16 out
// ---------------------------------------------------------------------------
template<int S>
__global__ __launch_bounds__(256) void ln_kernel(const float* __restrict__ X,
    const float* __restrict__ Y, const float* __restrict__ yb,
    const float* __restrict__ g, const float* __restrict__ bta,
    float* __restrict__ Of, bf16* __restrict__ Ob) {
  int row = blockIdx.x, t = threadIdx.x;
  const float* xp = X + (size_t)row * 768;
  float vals[3]; float s = 0.f, s2 = 0.f;
#pragma unroll
  for (int i = 0; i < 3; i++) {
    int e = t + 256 * i;
    float v = xp[e] + yb[e];
#pragma unroll
    for (int p = 0; p < S; p++) v += Y[(size_t)p * 786432 + (size_t)row * 768 + e];
    vals[i] = v; s += v; s2 = fmaf(v, v, s2);
  }
#pragma unroll
  for (int off = 32; off > 0; off >>= 1) { s += __shfl_xor(s, off); s2 += __shfl_xor(s2, off); }
  __shared__ float rs[4], rs2[4];
  if ((t & 63) == 0) { rs[t >> 6] = s; rs2[t >> 6] = s2; }
  __syncthreads();
  s = rs[0] + rs[1] + rs[2] + rs[3];
  s2 = rs2[0] + rs2[1] + rs2[2] + rs2[3];
  float mean = s * (1.f / 768.f);
  float var = s2 * (1.f / 768.f) - mean * mean;
  float rstd = rsqrtf(var + 1e-6f);
  float* ofp = Of + (size_t)row * 768;
  bf16* obp = Ob + (size_t)row * 768;
#pragma unroll
  for (int i = 0; i < 3; i++) {
    int e = t + 256 * i;
    float o = (vals[i] - mean) * rstd * g[e] + bta[e];
    ofp[e] = o; obp[e] = (bf16)o;
  }
}

// proj 2-partial reduce + bias -> tf fp32 + tb bf16
__global__ __launch_bounds__(256) void reduce2(const float* __restrict__ P,
    const float* __restrict__ bias, float* __restrict__ Of, bf16* __restrict__ Ob) {
  int row = blockIdx.x, t = threadIdx.x;
#pragma unroll
  for (int i = 0; i < 3; i++) {
    int e = t + 256 * i;
    float v = P[(size_t)row * 768 + e] + P[786432 + (size_t)row * 768 + e] + bias[e];
    Of[(size_t)row * 768 + e] = v;
    Ob[(size_t)row * 768 + e] = (bf16)v;
  }
}

// ---------------------------------------------------------------------------
// mean-pool + head + sigmoid
// ---------------------------------------------------------------------------
__global__ __launch_bounds__(256) void head_kernel(const float* __restrict__ T,
    const float* __restrict__ hw, const float* __restrict__ hbp, float* __restrict__ out) {
  int b = blockIdx.x, t = threadIdx.x;
  float acc = 0.f;
#pragma unroll
  for (int i = 0; i < 3; i++) {
    int e = t + 256 * i;
    float s = 0.f;
    for (int si = 0; si < 64; si++) s += T[(size_t)(b * 64 + si) * 768 + e];
    acc = fmaf(s * (1.f / 64.f), hw[e], acc);
  }
#pragma unroll
  for (int off = 32; off > 0; off >>= 1) acc += __shfl_xor(acc, off);
  __shared__ float rs[4];
  if ((t & 63) == 0) rs[t >> 6] = acc;
  __syncthreads();
  if (t == 0) {
    float z = rs[0] + rs[1] + rs[2] + rs[3] + hbp[0];
    out[b] = 1.f / (1.f + expf(-z));
  }
}

// ---------------------------------------------------------------------------
extern "C" void kernel_launch(void* const* d_in, const int* in_sizes, int n_in,
                              void* d_out, int out_size, void* d_ws, size_t ws_size,
                              hipStream_t stream) {
  const float* x     = (const float*)d_in[0];
  const float* c1w   = (const float*)d_in[1];
  const float* c1b   = (const float*)d_in[2];
  const float* c2w   = (const float*)d_in[3];
  const float* c2b   = (const float*)d_in[4];
  const float* projw = (const float*)d_in[5];
  const float* projb = (const float*)d_in[6];
  const float* Wq    = (const float*)d_in[7];
  const float* bq    = (const float*)d_in[8];
  const float* Wk    = (const float*)d_in[9];
  const float* bk    = (const float*)d_in[10];
  const float* Wv    = (const float*)d_in[11];
  const float* bv    = (const float*)d_in[12];
  const float* Wo    = (const float*)d_in[13];
  const float* bo    = (const float*)d_in[14];
  const float* W1    = (const float*)d_in[15];
  const float* b1    = (const float*)d_in[16];
  const float* W2    = (const float*)d_in[17];
  const float* b2    = (const float*)d_in[18];
  const float* ln1g  = (const float*)d_in[19];
  const float* ln1b  = (const float*)d_in[20];
  const float* ln2g  = (const float*)d_in[21];
  const float* ln2b  = (const float*)d_in[22];
  const float* headw = (const float*)d_in[23];
  const float* headb = (const float*)d_in[24];
  float* out = (float*)d_out;

  char* wp = (char*)d_ws;
  auto alloc = [&](size_t bytes) { char* p = wp; wp += (bytes + 255) & ~(size_t)255; return p; };
  bf16* c1p     = (bf16*)alloc((size_t)16 * 255 * 255 * 16 * 2);   // 33.3 MB
  bf16* patches = (bf16*)alloc((size_t)1024 * 4096 * 2);           // 8.4 MB
  bf16* projT   = (bf16*)alloc((size_t)4096 * 768 * 2);
  bf16* WqT     = (bf16*)alloc((size_t)8 * 768 * 768 * 2);
  bf16* WkT     = (bf16*)alloc((size_t)8 * 768 * 768 * 2);
  bf16* WvT     = (bf16*)alloc((size_t)8 * 768 * 768 * 2);
  bf16* WoT     = (bf16*)alloc((size_t)8 * 768 * 768 * 2);
  bf16* W1T     = (bf16*)alloc((size_t)8 * 768 * 3072 * 2);
  bf16* W2T     = (bf16*)alloc((size_t)8 * 3072 * 768 * 2);
  float* pp     = (float*)alloc((size_t)2 * 1024 * 768 * 4);       // proj partials
  float* tf     = (float*)alloc((size_t)1024 * 768 * 4);
  bf16*  tb     = (bf16*)alloc((size_t)1024 * 768 * 2);
  float* qp     = (float*)alloc((size_t)2 * 1024 * 768 * 4);
  float* kp     = (float*)alloc((size_t)2 * 1024 * 768 * 4);
  float* vp     = (float*)alloc((size_t)2 * 1024 * 768 * 4);
  float* wop    = (float*)alloc((size_t)2 * 1024 * 768 * 4);
  float* w2p    = (float*)alloc((size_t)4 * 1024 * 768 * 4);
  bf16*  ab     = (bf16*)alloc((size_t)1024 * 768 * 2);
  float* o1f    = (float*)alloc((size_t)1024 * 768 * 4);
  bf16*  o1b    = (bf16*)alloc((size_t)1024 * 768 * 2);
  bf16*  hbuf   = (bf16*)alloc((size_t)1024 * 3072 * 2);

  // weight prep
  wtrans<<<dim3(24, 128, 1), 256, 0, stream>>>(projw, projT, 4096, 768);
  wtrans<<<dim3(24, 24, 8), 256, 0, stream>>>(Wq, WqT, 768, 768);
  wtrans<<<dim3(24, 24, 8), 256, 0, stream>>>(Wk, WkT, 768, 768);
  wtrans<<<dim3(24, 24, 8), 256, 0, stream>>>(Wv, WvT, 768, 768);
  wtrans<<<dim3(24, 24, 8), 256, 0, stream>>>(Wo, WoT, 768, 768);
  wtrans<<<dim3(96, 24, 8), 256, 0, stream>>>(W1, W1T, 768, 3072);
  wtrans<<<dim3(24, 96, 8), 256, 0, stream>>>(W2, W2T, 3072, 768);

  conv1_mfma<<<dim3(16, 16, 16), 256, 0, stream>>>(x, c1w, c1b, c1p);
  conv2_mfma<<<dim3(8, 8, 16), 256, 0, stream>>>(c1p, c2w, c2b, patches);
  gemm_std<0><<<dim3(6, 8, 2), 256, 0, stream>>>(patches, projT, nullptr, pp, nullptr, 768, 4096, 2048);
  reduce2<<<1024, 256, 0, stream>>>(pp, projb, tf, tb);

  for (int i = 0; i < 8; i++) {
    gemm_qkv<<<dim3(6, 8, 6), 256, 0, stream>>>(tb,
        WqT + (size_t)i * 589824, WkT + (size_t)i * 589824, WvT + (size_t)i * 589824,
        qp, kp, vp);
    attn_kernel<<<192, 256, 0, stream>>>(qp, kp, vp,
        bq + i * 768, bk + i * 768, bv + i * 768, ab);
    gemm_std<0><<<dim3(6, 8, 2), 256, 0, stream>>>(ab, WoT + (size_t)i * 589824,
        nullptr, wop, nullptr, 768, 768, 384);
    ln_kernel<2><<<1024, 256, 0, stream>>>(tf, wop, bo + i * 768,
        ln1g + i * 768, ln1b + i * 768, o1f, o1b);
    gemm_std<1><<<dim3(24, 8, 1), 256, 0, stream>>>(o1b, W1T + (size_t)i * 2359296,
        b1 + i * 3072, nullptr, hbuf, 3072, 768, 768);
    gemm_std<0><<<dim3(6, 8, 4), 256, 0, stream>>>(hbuf, W2T + (size_t)i * 2359296,
        nullptr, w2p, nullptr, 768, 3072, 768);
    ln_kernel<4><<<1024, 256, 0, stream>>>(o1f, w2p, b2 + i * 768,
        ln2g + i * 768, ln2b + i * 768, tf, tb);
  }
  head_kernel<<<16, 256, 0, stream>>>(tf, headw, headb, out);
}

// Round 4
// 910.404 us; speedup vs baseline: 1.5754x; 1.5754x over previous
//
#include <hip/hip_runtime.h>
#include <hip/hip_bf16.h>
#include <cstdint>
#include <cstddef>

typedef __bf16 bf16;
typedef __attribute__((ext_vector_type(8))) __bf16 bf16x8;
typedef __attribute__((ext_vector_type(4))) float f32x4;

// ---------------------------------------------------------------------------
// weight transpose+cast: src (L,K,N) fp32 -> dst (L,N,K) bf16. grid(N/32,K/32,L)
// ---------------------------------------------------------------------------
__global__ __launch_bounds__(256) void wtrans(const float* __restrict__ src,
    bf16* __restrict__ dst, int K, int N) {
  __shared__ float tile[32][33];
  int l = blockIdx.z;
  src += (size_t)l * K * N; dst += (size_t)l * K * N;
  int n0 = blockIdx.x * 32, k0 = blockIdx.y * 32;
  int tx = threadIdx.x & 31, ty = threadIdx.x >> 5;
#pragma unroll
  for (int i = 0; i < 4; i++) {
    int k = ty + i * 8;
    tile[k][tx] = src[(size_t)(k0 + k) * N + n0 + tx];
  }
  __syncthreads();
#pragma unroll
  for (int i = 0; i < 4; i++) {
    int n = ty + i * 8;
    dst[(size_t)(n0 + n) * K + k0 + tx] = (bf16)tile[tx][n];
  }
}

// ---------------------------------------------------------------------------
// conv1 (3x3, 3->16, VALID) + ReLU + maxpool 2x2 via MFMA (implicit im2col).
// x (16,512,512,3) fp32 -> out bf16 (16,255,255,16).
// Block = 16x16 pooled outputs; grid (16,16,16), 4 waves.
// ---------------------------------------------------------------------------
__global__ __launch_bounds__(256) void conv1_mfma(const float* __restrict__ x,
    const float* __restrict__ w, const float* __restrict__ bias,
    bf16* __restrict__ out) {
  __shared__ alignas(16) bf16 xs[34 * 35 * 8];   // 19040 B
  int t = threadIdx.x;
  int bx = blockIdx.x, by = blockIdx.y, b = blockIdx.z;
  int r0 = 32 * by, c0 = 32 * bx;
  for (int i = t; i < 34 * 35; i += 256) {
    int rr = i / 35, cc = i % 35;
    int gr = min(r0 + rr, 511), gc = min(c0 + cc, 511);
    const float* ip = x + ((size_t)(b * 512 + gr) * 512 + gc) * 3;
    bf16x8 pv = {(bf16)ip[0], (bf16)ip[1], (bf16)ip[2],
                 (bf16)0.f, (bf16)0.f, (bf16)0.f, (bf16)0.f, (bf16)0.f};
    *(bf16x8*)&xs[i * 8] = pv;
  }
  int lane = t & 63, wave = t >> 6;
  int lr = lane & 15, lq = lane >> 4;
  bf16x8 bfrag[3];
#pragma unroll
  for (int ky = 0; ky < 3; ky++) {
    bf16x8 v;
#pragma unroll
    for (int j = 0; j < 8; j++)
      v[j] = (lq < 3 && j < 3) ? (bf16)w[((ky * 3 + lq) * 3 + j) * 16 + lr] : (bf16)0.f;
    bfrag[ky] = v;
  }
  float bco = bias[lr];
  __syncthreads();
#pragma unroll
  for (int yy = 0; yy < 4; yy++) {
    int Y = wave * 4 + yy;            // pooled row within tile
    int yp = by * 16 + Y;
    int cy = 2 * Y;                   // conv row (halo-local)
#pragma unroll
    for (int hx = 0; hx < 2; hx++) {
      f32x4 a0 = {0.f, 0.f, 0.f, 0.f}, a1 = {0.f, 0.f, 0.f, 0.f};
      int pbase = hx * 16 + lr + lq;  // A row = conv-x (lr), octet = kx (lq)
#pragma unroll
      for (int ky = 0; ky < 3; ky++) {
        bf16x8 f0 = *(const bf16x8*)&xs[((cy + ky) * 35 + pbase) * 8];
        a0 = __builtin_amdgcn_mfma_f32_16x16x32_bf16(f0, bfrag[ky], a0, 0, 0, 0);
      }
#pragma unroll
      for (int ky = 0; ky < 3; ky++) {
        bf16x8 f1 = *(const bf16x8*)&xs[((cy + 1 + ky) * 35 + pbase) * 8];
        a1 = __builtin_amdgcn_mfma_f32_16x16x32_bf16(f1, bfrag[ky], a1, 0, 0, 0);
      }
      float m0 = fmaxf(fmaxf(a0[0], a0[1]), fmaxf(a1[0], a1[1]));
      float m1 = fmaxf(fmaxf(a0[2], a0[3]), fmaxf(a1[2], a1[3]));
      m0 = fmaxf(m0 + bco, 0.f);
      m1 = fmaxf(m1 + bco, 0.f);
      int xp0 = bx * 16 + hx * 8 + 2 * lq, xp1 = xp0 + 1;
      if (yp < 255) {
        bf16* op = out + ((size_t)(b * 255 + yp) * 255) * 16 + lr;
        if (xp0 < 255) op[xp0 * 16] = (bf16)m0;
        if (xp1 < 255) op[xp1 * 16] = (bf16)m1;
      }
    }
  }
}

// ---------------------------------------------------------------------------
// conv2 + ReLU + maxpool + pad(1) + patch-extract via MFMA (implicit im2col).
// in bf16 (16,255,255,16); block = one 16x16 patch; grid (8,8,16), 4 waves.
// ---------------------------------------------------------------------------
__global__ __launch_bounds__(256) void conv2_mfma(const bf16* __restrict__ in,
    const float* __restrict__ w, const float* __restrict__ bias,
    bf16* __restrict__ patches) {
  __shared__ alignas(16) bf16 xlo[1156 * 8];   // 34x34 positions, ch 0-7
  __shared__ alignas(16) bf16 xhi[1156 * 8];   // ch 8-15
  __shared__ float ws[2304];
  int t = threadIdx.x;
  int tx = blockIdx.x, ty = blockIdx.y, b = blockIdx.z;
  for (int i = t; i < 2304; i += 256) ws[i] = w[i];
  int r0 = 32 * ty - 2, c0 = 32 * tx - 2;
  for (int i = t; i < 1156; i += 256) {
    int rr = i / 34, cc = i % 34;
    int gr = min(max(r0 + rr, 0), 254), gc = min(max(c0 + cc, 0), 254);
    const bf16* ip = in + ((size_t)(b * 255 + gr) * 255 + gc) * 16;
    *(uint4*)&xlo[i * 8] = *(const uint4*)ip;
    *(uint4*)&xhi[i * 8] = *(const uint4*)(ip + 8);
  }
  __syncthreads();
  int lane = t & 63, wave = t >> 6;
  int lr = lane & 15, lq = lane >> 4;
  int tapsel = lq >> 1;
  int ci0 = (lq & 1) * 8;
  bf16x8 bfrag[5];
  int koff[5];   // (ky*34 + kx) address offset for this lane's tap, per chunk
#pragma unroll
  for (int c2 = 0; c2 < 5; c2++) {
    int tap = 2 * c2 + tapsel;
    bf16x8 v;
#pragma unroll
    for (int j = 0; j < 8; j++)
      v[j] = (tap < 9) ? (bf16)ws[tap * 256 + (ci0 + j) * 16 + lr] : (bf16)0.f;
    bfrag[c2] = v;
    int tc = min(tap, 8);                    // pad tap reads tap-8 addr (x 0 weight)
    koff[c2] = (tc / 3) * 34 + (tc % 3);
  }
  const bf16* plane = (lq & 1) ? xhi : xlo;
  float bco = bias[lr];
  bf16* pout = patches + ((size_t)(b * 64 + ty * 8 + tx) * 4096);
#pragma unroll
  for (int yy = 0; yy < 4; yy++) {
    int Y = wave * 4 + yy;
    int yp = ty * 16 + Y;
    bool padrow = (yp == 0 || yp == 127);
#pragma unroll
    for (int hx = 0; hx < 2; hx++) {
      f32x4 a0 = {0.f, 0.f, 0.f, 0.f}, a1 = {0.f, 0.f, 0.f, 0.f};
      int base0 = (2 * Y) * 34 + hx * 16 + lr;   // conv row 2Y, x = hx*16+lr
      int base1 = base0 + 34;                    // conv row 2Y+1
#pragma unroll
      for (int c2 = 0; c2 < 5; c2++) {
        bf16x8 f0 = *(const bf16x8*)&plane[(base0 + koff[c2]) * 8];
        a0 = __builtin_amdgcn_mfma_f32_16x16x32_bf16(f0, bfrag[c2], a0, 0, 0, 0);
      }
#pragma unroll
      for (int c2 = 0; c2 < 5; c2++) {
        bf16x8 f1 = *(const bf16x8*)&plane[(base1 + koff[c2]) * 8];
        a1 = __builtin_amdgcn_mfma_f32_16x16x32_bf16(f1, bfrag[c2], a1, 0, 0, 0);
      }
      float m0 = fmaxf(fmaxf(a0[0], a0[1]), fmaxf(a1[0], a1[1]));
      float m1 = fmaxf(fmaxf(a0[2], a0[3]), fmaxf(a1[2], a1[3]));
      m0 = fmaxf(m0 + bco, 0.f);
      m1 = fmaxf(m1 + bco, 0.f);
      int px0 = hx * 8 + 2 * lq, px1 = px0 + 1;
      int xp0 = tx * 16 + px0, xp1 = xp0 + 1;
      if (padrow || xp0 == 0) m0 = 0.f;      // xp0==127 impossible (even)
      if (padrow || xp1 == 127) m1 = 0.f;    // xp1==0 impossible (odd)
      pout[Y * 256 + px0 * 16 + lr] = (bf16)m0;
      pout[Y * 256 + px1 * 16 + lr] = (bf16)m1;
    }
  }
}

// ---------------------------------------------------------------------------
// bf16 MFMA GEMM: C = A(M,K) @ Bt(N,K)^T. 64x64 tile, BK=64, 4 waves 2x2,
// register-pipelined global prefetch. A,Bt bf16 K-major (16B vector staging).
// MODE 0: fp32 partial, no bias. MODE 1: bias+relu -> bf16.
// (Round-2 proven version; LDS-free variant regressed: latency-bound at 4% occ)
// ---------------------------------------------------------------------------
#define LSTR 72

template<int MODE>
__device__ __forceinline__ void gemm_core(const bf16* __restrict__ A,
    const bf16* __restrict__ Bt, const float* __restrict__ bias,
    float* __restrict__ Cf, bf16* __restrict__ Cb,
    int bm, int bn, int N, int K, int k0, int kc) {
  __shared__ alignas(16) bf16 As[64 * LSTR];
  __shared__ alignas(16) bf16 Bs[64 * LSTR];
  int t = threadIdx.x, lane = t & 63, wave = t >> 6;
  int wm = (wave >> 1) * 32, wn = (wave & 1) * 32;
  int lq = lane >> 4, lr = lane & 15;
  f32x4 acc[2][2];
#pragma unroll
  for (int i = 0; i < 2; i++)
#pragma unroll
  for (int j = 0; j < 2; j++) acc[i][j] = (f32x4){0.f, 0.f, 0.f, 0.f};
  int r = t >> 2, c = (t & 3) * 16;
  const bf16* Ap = A + (size_t)(bm + r) * K + k0 + c;
  const bf16* Bp = Bt + (size_t)(bn + r) * K + k0 + c;
  bf16* AsW = &As[r * LSTR + c];
  bf16* BsW = &Bs[r * LSTR + c];
  uint4 a0 = *(const uint4*)Ap, a1 = *(const uint4*)(Ap + 8);
  uint4 b0 = *(const uint4*)Bp, b1 = *(const uint4*)(Bp + 8);
  for (int kk = 64; kk <= kc; kk += 64) {
    *(uint4*)AsW = a0; *(uint4*)(AsW + 8) = a1;
    *(uint4*)BsW = b0; *(uint4*)(BsW + 8) = b1;
    __syncthreads();
    if (kk < kc) {   // prefetch next K-tile while MFMA runs
      Ap += 64; Bp += 64;
      a0 = *(const uint4*)Ap; a1 = *(const uint4*)(Ap + 8);
      b0 = *(const uint4*)Bp; b1 = *(const uint4*)(Bp + 8);
    }
#pragma unroll
    for (int ks = 0; ks < 2; ks++) {
      bf16x8 af0 = *(const bf16x8*)&As[(wm + lr) * LSTR + ks * 32 + lq * 8];
      bf16x8 af1 = *(const bf16x8*)&As[(wm + 16 + lr) * LSTR + ks * 32 + lq * 8];
      bf16x8 bfr0 = *(const bf16x8*)&Bs[(wn + lr) * LSTR + ks * 32 + lq * 8];
      bf16x8 bfr1 = *(const bf16x8*)&Bs[(wn + 16 + lr) * LSTR + ks * 32 + lq * 8];
      acc[0][0] = __builtin_amdgcn_mfma_f32_16x16x32_bf16(af0, bfr0, acc[0][0], 0, 0, 0);
      acc[0][1] = __builtin_amdgcn_mfma_f32_16x16x32_bf16(af0, bfr1, acc[0][1], 0, 0, 0);
      acc[1][0] = __builtin_amdgcn_mfma_f32_16x16x32_bf16(af1, bfr0, acc[1][0], 0, 0, 0);
      acc[1][1] = __builtin_amdgcn_mfma_f32_16x16x32_bf16(af1, bfr1, acc[1][1], 0, 0, 0);
    }
    __syncthreads();
  }
#pragma unroll
  for (int mi = 0; mi < 2; mi++)
#pragma unroll
  for (int ni = 0; ni < 2; ni++) {
    int col = bn + wn + ni * 16 + lr;
#pragma unroll
    for (int rr = 0; rr < 4; rr++) {
      int row = bm + wm + mi * 16 + lq * 4 + rr;   // m89-verified C/D layout
      float v = acc[mi][ni][rr];
      if (MODE == 1) {
        v = fmaxf(v + bias[col], 0.f);
        Cb[(size_t)row * N + col] = (bf16)v;
      } else {
        Cf[(size_t)row * N + col] = v;
      }
    }
  }
}

template<int MODE>
__global__ __launch_bounds__(256) void gemm_std(const bf16* __restrict__ A,
    const bf16* __restrict__ Bt, const float* __restrict__ bias,
    float* __restrict__ Cf, bf16* __restrict__ Cb, int N, int K, int KC) {
  int s = blockIdx.z;
  float* Cfp = Cf ? Cf + (size_t)s * 1024 * N : nullptr;
  gemm_core<MODE>(A, Bt, bias, Cfp, Cb, blockIdx.y * 64, blockIdx.x * 64, N, K, s * KC, KC);
}

__global__ __launch_bounds__(256) void gemm_qkv(const bf16* __restrict__ A,
    const bf16* __restrict__ Btq, const bf16* __restrict__ Btk, const bf16* __restrict__ Btv,
    float* __restrict__ qp, float* __restrict__ kp, float* __restrict__ vp) {
  int z = blockIdx.z;               // 0..5 : sel*2 + split
  int sel = z >> 1, s = z & 1;
  const bf16* Bt = (sel == 0) ? Btq : (sel == 1) ? Btk : Btv;
  float* C = ((sel == 0) ? qp : (sel == 1) ? kp : vp) + (size_t)s * 786432;
  gemm_core<0>(A, Bt, nullptr, C, nullptr, blockIdx.y * 64, blockIdx.x * 64, 768, 768, s * 384, 384);
}

// ---------------------------------------------------------------------------
// attention via MFMA: one block per (b,h), 4 waves, S=64, D=64.
// q,k,v are 2-way split-K fp32 partials (2,1024,768); bias added at staging,
// converted to bf16. Q,K staged [s][d] (A / B^T layouts), V^T staged [d][s].
// Each wave owns 16 q-rows: QK^T = 8 MFMA, softmax fully in-register on the
// C/D layout (row=lq*4+rr, cols over lr x 4 frags; shfl_xor over 16-lane
// group), P -> LDS bf16 once (re-enter A layout), PV = 8 MFMA.
// Output (B,H,S,D)-flat bf16 (reference quirk). 2 barriers total.
// ---------------------------------------------------------------------------
__global__ __launch_bounds__(256) void attn_kernel(const float* __restrict__ Qp,
    const float* __restrict__ Kp, const float* __restrict__ Vp,
    const float* __restrict__ bq, const float* __restrict__ bk, const float* __restrict__ bv,
    bf16* __restrict__ Aout) {
  __shared__ alignas(16) bf16 qs[64 * 72];
  __shared__ alignas(16) bf16 ks[64 * 72];
  __shared__ alignas(16) bf16 vt[64 * 72];   // V^T [d][s]
  __shared__ alignas(16) bf16 ps[64 * 72];   // softmax P [q][s]
  int t = threadIdx.x;
  int bh = blockIdx.x; int b = bh / 12, h = bh % 12;
  size_t base = (size_t)b * 49152 + h * 64;
  const float* qb0 = Qp + base; const float* qb1 = qb0 + 786432;
  const float* kb0 = Kp + base; const float* kb1 = kb0 + 786432;
  const float* vb0 = Vp + base; const float* vb1 = vb0 + 786432;
  {
    int s = t >> 2, d0 = (t & 3) * 16;
    alignas(16) bf16 qv[16], kv[16];
#pragma unroll
    for (int j = 0; j < 16; j += 4) {
      float4 q0 = *(const float4*)(qb0 + (size_t)s * 768 + d0 + j);
      float4 q1 = *(const float4*)(qb1 + (size_t)s * 768 + d0 + j);
      float4 qb4 = *(const float4*)(bq + h * 64 + d0 + j);
      float4 k0 = *(const float4*)(kb0 + (size_t)s * 768 + d0 + j);
      float4 k1 = *(const float4*)(kb1 + (size_t)s * 768 + d0 + j);
      float4 kb4 = *(const float4*)(bk + h * 64 + d0 + j);
      qv[j + 0] = (bf16)(q0.x + q1.x + qb4.x);
      qv[j + 1] = (bf16)(q0.y + q1.y + qb4.y);
      qv[j + 2] = (bf16)(q0.z + q1.z + qb4.z);
      qv[j + 3] = (bf16)(q0.w + q1.w + qb4.w);
      kv[j + 0] = (bf16)(k0.x + k1.x + kb4.x);
      kv[j + 1] = (bf16)(k0.y + k1.y + kb4.y);
      kv[j + 2] = (bf16)(k0.z + k1.z + kb4.z);
      kv[j + 3] = (bf16)(k0.w + k1.w + kb4.w);
    }
    *(uint4*)&qs[s * 72 + d0] = *(uint4*)&qv[0];
    *(uint4*)&qs[s * 72 + d0 + 8] = *(uint4*)&qv[8];
    *(uint4*)&ks[s * 72 + d0] = *(uint4*)&kv[0];
    *(uint4*)&ks[s * 72 + d0 + 8] = *(uint4*)&kv[8];
    // V^T staging: thread owns (d, 16 s-values)
    int d = t & 63, s0 = (t >> 6) * 16;
    float bvd = bv[h * 64 + d];
    alignas(16) bf16 vv[16];
#pragma unroll
    for (int i = 0; i < 16; i++)
      vv[i] = (bf16)(vb0[(size_t)(s0 + i) * 768 + d] + vb1[(size_t)(s0 + i) * 768 + d] + bvd);
    *(uint4*)&vt[d * 72 + s0] = *(uint4*)&vv[0];
    *(uint4*)&vt[d * 72 + s0 + 8] = *(uint4*)&vv[8];
  }
  __syncthreads();
  int lane = t & 63, wave = t >> 6;
  int lr = lane & 15, lq = lane >> 4;
  int r0 = wave * 16;                 // this wave's q-row base
  f32x4 sc[4];
#pragma unroll
  for (int j = 0; j < 4; j++) sc[j] = (f32x4){0.f, 0.f, 0.f, 0.f};
#pragma unroll
  for (int kslice = 0; kslice < 2; kslice++) {
    bf16x8 a = *(const bf16x8*)&qs[(r0 + lr) * 72 + kslice * 32 + lq * 8];
#pragma unroll
    for (int nj = 0; nj < 4; nj++) {
      bf16x8 bb = *(const bf16x8*)&ks[(nj * 16 + lr) * 72 + kslice * 32 + lq * 8];
      sc[nj] = __builtin_amdgcn_mfma_f32_16x16x32_bf16(a, bb, sc[nj], 0, 0, 0);
    }
  }
#pragma unroll
  for (int nj = 0; nj < 4; nj++)
#pragma unroll
  for (int rr = 0; rr < 4; rr++) sc[nj][rr] *= 0.125f;
  // softmax: lane's rows are r0 + lq*4 + rr; row spans 16 lanes (lr) x 4 frags
  float pw[4][4];                     // [nj][rr]
#pragma unroll
  for (int rr = 0; rr < 4; rr++) {
    float m = fmaxf(fmaxf(sc[0][rr], sc[1][rr]), fmaxf(sc[2][rr], sc[3][rr]));
#pragma unroll
    for (int off = 1; off < 16; off <<= 1) m = fmaxf(m, __shfl_xor(m, off));
    float e0 = __expf(sc[0][rr] - m), e1 = __expf(sc[1][rr] - m);
    float e2 = __expf(sc[2][rr] - m), e3 = __expf(sc[3][rr] - m);
    float sm = e0 + e1 + e2 + e3;
#pragma unroll
    for (int off = 1; off < 16; off <<= 1) sm += __shfl_xor(sm, off);
    float inv = 1.f / sm;
    pw[0][rr] = e0 * inv; pw[1][rr] = e1 * inv;
    pw[2][rr] = e2 * inv; pw[3][rr] = e3 * inv;
  }
#pragma unroll
  for (int nj = 0; nj < 4; nj++)
#pragma unroll
  for (int rr = 0; rr < 4; rr++)
    ps[(r0 + lq * 4 + rr) * 72 + nj * 16 + lr] = (bf16)pw[nj][rr];
  __syncthreads();
  f32x4 oc[4];
#pragma unroll
  for (int j = 0; j < 4; j++) oc[j] = (f32x4){0.f, 0.f, 0.f, 0.f};
#pragma unroll
  for (int kslice = 0; kslice < 2; kslice++) {
    bf16x8 a = *(const bf16x8*)&ps[(r0 + lr) * 72 + kslice * 32 + lq * 8];
#pragma unroll
    for (int nj = 0; nj < 4; nj++) {
      bf16x8 bb = *(const bf16x8*)&vt[(nj * 16 + lr) * 72 + kslice * 32 + lq * 8];
      oc[nj] = __builtin_amdgcn_mfma_f32_16x16x32_bf16(a, bb, oc[nj], 0, 0, 0);
    }
  }
  bf16* ob = Aout + (size_t)b * 49152 + h * 4096;
#pragma unroll
  for (int nj = 0; nj < 4; nj++)
#pragma unroll
  for (int rr = 0; rr < 4; rr++)
    ob[(r0 + lq * 4 + rr) * 64 + nj * 16 + lr] = (bf16)oc[nj][rr];
}

// ---------------------------------------------------------------------------
// residual + S-way split-K partial sum + col bias + LayerNorm; fp32 + bf16 out
// ---------------------------------------------------------------------------
template<int S>
__global__ __launch_bounds__(256) void ln_kernel(const float* __restrict__ X,
    const float* __restrict__ Y, const float* __restrict__ yb,
    const float* __restrict__ g, const float* __restrict__ bta,
    float* __restrict__ Of, bf16* __restrict__ Ob) {
  int row = blockIdx.x, t = threadIdx.x;
  const float* xp = X + (size_t)row * 768;
  float vals[3]; float s = 0.f, s2 = 0.f;
#pragma unroll
  for (int i = 0; i < 3; i++) {
    int e = t + 256 * i;
    float v = xp[e] + yb[e];
#pragma unroll
    for (int p = 0; p < S; p++) v += Y[(size_t)p * 786432 + (size_t)row * 768 + e];
    vals[i] = v; s += v; s2 = fmaf(v, v, s2);
  }
#pragma unroll
  for (int off = 32; off > 0; off >>= 1) { s += __shfl_xor(s, off); s2 += __shfl_xor(s2, off); }
  __shared__ float rs[4], rs2[4];
  if ((t & 63) == 0) { rs[t >> 6] = s; rs2[t >> 6] = s2; }
  __syncthreads();
  s = rs[0] + rs[1] + rs[2] + rs[3];
  s2 = rs2[0] + rs2[1] + rs2[2] + rs2[3];
  float mean = s * (1.f / 768.f);
  float var = s2 * (1.f / 768.f) - mean * mean;
  float rstd = rsqrtf(var + 1e-6f);
  float* ofp = Of + (size_t)row * 768;
  bf16* obp = Ob + (size_t)row * 768;
#pragma unroll
  for (int i = 0; i < 3; i++) {
    int e = t + 256 * i;
    float o = (vals[i] - mean) * rstd * g[e] + bta[e];
    ofp[e] = o; obp[e] = (bf16)o;
  }
}

// proj 2-partial reduce + bias -> tf fp32 + tb bf16
__global__ __launch_bounds__(256) void reduce2(const float* __restrict__ P,
    const float* __restrict__ bias, float* __restrict__ Of, bf16* __restrict__ Ob) {
  int row = blockIdx.x, t = threadIdx.x;
#pragma unroll
  for (int i = 0; i < 3; i++) {
    int e = t + 256 * i;
    float v = P[(size_t)row * 768 + e] + P[786432 + (size_t)row * 768 + e] + bias[e];
    Of[(size_t)row * 768 + e] = v;
    Ob[(size_t)row * 768 + e] = (bf16)v;
  }
}

// ---------------------------------------------------------------------------
// mean-pool + head + sigmoid
// ---------------------------------------------------------------------------
__global__ __launch_bounds__(256) void head_kernel(const float* __restrict__ T,
    const float* __restrict__ hw, const float* __restrict__ hbp, float* __restrict__ out) {
  int b = blockIdx.x, t = threadIdx.x;
  float acc = 0.f;
#pragma unroll
  for (int i = 0; i < 3; i++) {
    int e = t + 256 * i;
    float s = 0.f;
    for (int si = 0; si < 64; si++) s += T[(size_t)(b * 64 + si) * 768 + e];
    acc = fmaf(s * (1.f / 64.f), hw[e], acc);
  }
#pragma unroll
  for (int off = 32; off > 0; off >>= 1) acc += __shfl_xor(acc, off);
  __shared__ float rs[4];
  if ((t & 63) == 0) rs[t >> 6] = acc;
  __syncthreads();
  if (t == 0) {
    float z = rs[0] + rs[1] + rs[2] + rs[3] + hbp[0];
    out[b] = 1.f / (1.f + expf(-z));
  }
}

// ---------------------------------------------------------------------------
extern "C" void kernel_launch(void* const* d_in, const int* in_sizes, int n_in,
                              void* d_out, int out_size, void* d_ws, size_t ws_size,
                              hipStream_t stream) {
  const float* x     = (const float*)d_in[0];
  const float* c1w   = (const float*)d_in[1];
  const float* c1b   = (const float*)d_in[2];
  const float* c2w   = (const float*)d_in[3];
  const float* c2b   = (const float*)d_in[4];
  const float* projw = (const float*)d_in[5];
  const float* projb = (const float*)d_in[6];
  const float* Wq    = (const float*)d_in[7];
  const float* bq    = (const float*)d_in[8];
  const float* Wk    = (const float*)d_in[9];
  const float* bk    = (const float*)d_in[10];
  const float* Wv    = (const float*)d_in[11];
  const float* bv    = (const float*)d_in[12];
  const float* Wo    = (const float*)d_in[13];
  const float* bo    = (const float*)d_in[14];
  const float* W1    = (const float*)d_in[15];
  const float* b1    = (const float*)d_in[16];
  const float* W2    = (const float*)d_in[17];
  const float* b2    = (const float*)d_in[18];
  const float* ln1g  = (const float*)d_in[19];
  const float* ln1b  = (const float*)d_in[20];
  const float* ln2g  = (const float*)d_in[21];
  const float* ln2b  = (const float*)d_in[22];
  const float* headw = (const float*)d_in[23];
  const float* headb = (const float*)d_in[24];
  float* out = (float*)d_out;

  char* wp = (char*)d_ws;
  auto alloc = [&](size_t bytes) { char* p = wp; wp += (bytes + 255) & ~(size_t)255; return p; };
  bf16* c1p     = (bf16*)alloc((size_t)16 * 255 * 255 * 16 * 2);   // 33.3 MB
  bf16* patches = (bf16*)alloc((size_t)1024 * 4096 * 2);           // 8.4 MB
  bf16* projT   = (bf16*)alloc((size_t)4096 * 768 * 2);
  bf16* WqT     = (bf16*)alloc((size_t)8 * 768 * 768 * 2);
  bf16* WkT     = (bf16*)alloc((size_t)8 * 768 * 768 * 2);
  bf16* WvT     = (bf16*)alloc((size_t)8 * 768 * 768 * 2);
  bf16* WoT     = (bf16*)alloc((size_t)8 * 768 * 768 * 2);
  bf16* W1T     = (bf16*)alloc((size_t)8 * 768 * 3072 * 2);
  bf16* W2T     = (bf16*)alloc((size_t)8 * 3072 * 768 * 2);
  float* pp     = (float*)alloc((size_t)2 * 1024 * 768 * 4);       // proj partials
  float* tf     = (float*)alloc((size_t)1024 * 768 * 4);
  bf16*  tb     = (bf16*)alloc((size_t)1024 * 768 * 2);
  float* qp     = (float*)alloc((size_t)2 * 1024 * 768 * 4);
  float* kp     = (float*)alloc((size_t)2 * 1024 * 768 * 4);
  float* vp     = (float*)alloc((size_t)2 * 1024 * 768 * 4);
  float* wop    = (float*)alloc((size_t)2 * 1024 * 768 * 4);
  float* w2p    = (float*)alloc((size_t)4 * 1024 * 768 * 4);
  bf16*  ab     = (bf16*)alloc((size_t)1024 * 768 * 2);
  float* o1f    = (float*)alloc((size_t)1024 * 768 * 4);
  bf16*  o1b    = (bf16*)alloc((size_t)1024 * 768 * 2);
  bf16*  hbuf   = (bf16*)alloc((size_t)1024 * 3072 * 2);

  // weight prep
  wtrans<<<dim3(24, 128, 1), 256, 0, stream>>>(projw, projT, 4096, 768);
  wtrans<<<dim3(24, 24, 8), 256, 0, stream>>>(Wq, WqT, 768, 768);
  wtrans<<<dim3(24, 24, 8), 256, 0, stream>>>(Wk, WkT, 768, 768);
  wtrans<<<dim3(24, 24, 8), 256, 0, stream>>>(Wv, WvT, 768, 768);
  wtrans<<<dim3(24, 24, 8), 256, 0, stream>>>(Wo, WoT, 768, 768);
  wtrans<<<dim3(96, 24, 8), 256, 0, stream>>>(W1, W1T, 768, 3072);
  wtrans<<<dim3(24, 96, 8), 256, 0, stream>>>(W2, W2T, 3072, 768);

  conv1_mfma<<<dim3(16, 16, 16), 256, 0, stream>>>(x, c1w, c1b, c1p);
  conv2_mfma<<<dim3(8, 8, 16), 256, 0, stream>>>(c1p, c2w, c2b, patches);
  gemm_std<0><<<dim3(12, 16, 2), 256, 0, stream>>>(patches, projT, nullptr, pp, nullptr, 768, 4096, 2048);
  reduce2<<<1024, 256, 0, stream>>>(pp, projb, tf, tb);

  for (int i = 0; i < 8; i++) {
    gemm_qkv<<<dim3(12, 16, 6), 256, 0, stream>>>(tb,
        WqT + (size_t)i * 589824, WkT + (size_t)i * 589824, WvT + (size_t)i * 589824,
        qp, kp, vp);
    attn_kernel<<<192, 256, 0, stream>>>(qp, kp, vp,
        bq + i * 768, bk + i * 768, bv + i * 768, ab);
    gemm_std<0><<<dim3(12, 16, 2), 256, 0, stream>>>(ab, WoT + (size_t)i * 589824,
        nullptr, wop, nullptr, 768, 768, 384);
    ln_kernel<2><<<1024, 256, 0, stream>>>(tf, wop, bo + i * 768,
        ln1g + i * 768, ln1b + i * 768, o1f, o1b);
    gemm_std<1><<<dim3(48, 16, 1), 256, 0, stream>>>(o1b, W1T + (size_t)i * 2359296,
        b1 + i * 3072, nullptr, hbuf, 3072, 768, 768);
    gemm_std<0><<<dim3(12, 16, 4), 256, 0, stream>>>(hbuf, W2T + (size_t)i * 2359296,
        nullptr, w2p, nullptr, 768, 3072, 768);
    ln_kernel<4><<<1024, 256, 0, stream>>>(o1f, w2p, b2 + i * 768,
        ln2g + i * 768, ln2b + i * 768, tf, tb);
  }
  head_kernel<<<16, 256, 0, stream>>>(tf, headw, headb, out);
}